// Round 14
// baseline (36.971 us; speedup 1.0000x reference)
//
#include <hip/hip_runtime.h>
#include <cfloat>

// Problem dims (fixed by reference)
#define BB   256   // batch
#define DIM  512
#define NN   196

typedef __attribute__((ext_vector_type(8))) short bf16x8;   // 8 bf16 (4 VGPRs)
typedef __attribute__((ext_vector_type(4))) float f32x4;    // MFMA acc

__device__ __forceinline__ ushort f2bf(float x) {          // RNE f32->bf16
    unsigned u = __float_as_uint(x);
    return (ushort)((u + 0x7FFFu + ((u >> 16) & 1u)) >> 16);
}

// ---------------------------------------------------------------------------
// Kernel 0: convert — build bf16 operands in d_ws.  Re-gridded for occupancy:
// 832 blocks (512 Wc + 64 WmT + 256 mu) ~ 3.3 blocks/CU, 13 waves/CU.
//   Wt[0][i][k] = bf16(W_mem[k][i])  (transposed)
//   Wt[1][i][k] = bf16(W_concat[i][k]) ; Wt[2][i][k] = bf16(W_concat[DIM+i][k])
//   mu[0][b][k] = bf16(memory[-1][b][k]) ; mu[1][b][k] = bf16(ctl[-1][b][k]*W_attn[k])
// ---------------------------------------------------------------------------
__global__ __launch_bounds__(256) void convert_kernel(
    const float* __restrict__ memory, const float* __restrict__ control,
    const float* __restrict__ W_mem, const float* __restrict__ W_concat,
    const float* __restrict__ W_attn,
    ushort* __restrict__ Wt,      // [3][512][512] bf16
    ushort* __restrict__ mu)      // [2][256][512] bf16
{
    const int tid = threadIdx.x;
    const int blk = blockIdx.x;

    if (blk < 512) {
        // ---- W_concat straight convert: 131072 float4, 1 per thread ----
        const int idx = blk * 256 + tid;
        const float4 q = ((const float4*)W_concat)[idx];
        uint2 o;
        o.x = (unsigned)f2bf(q.x) | ((unsigned)f2bf(q.y) << 16);
        o.y = (unsigned)f2bf(q.z) | ((unsigned)f2bf(q.w) << 16);
        ((uint2*)(Wt + (size_t)DIM * DIM))[idx] = o;
    } else if (blk < 576) {
        // ---- W_mem transpose-convert, 64x64 tile via LDS ----
        __shared__ float T[64][65];
        const int t  = blk - 512;
        const int tk = (t >> 3) * 64, ti = (t & 7) * 64;
        const int r  = tid >> 2;            // k-local row
        const int cb = (tid & 3) * 16;      // i-local col base
        #pragma unroll
        for (int j = 0; j < 16; j += 4) {
            const float4 q = *(const float4*)&W_mem[(size_t)(tk + r) * DIM + ti + cb + j];
            T[r][cb + j + 0] = q.x; T[r][cb + j + 1] = q.y;
            T[r][cb + j + 2] = q.z; T[r][cb + j + 3] = q.w;
        }
        __syncthreads();
        const int ii = tid & 63;            // i-local
        const int kq = tid >> 6;            // 0..3
        #pragma unroll
        for (int kk = 0; kk < 16; kk += 2) {
            const int k = kq * 16 + kk;
            const unsigned v = (unsigned)f2bf(T[k][ii]) | ((unsigned)f2bf(T[k + 1][ii]) << 16);
            *(unsigned*)&Wt[(size_t)(ti + ii) * DIM + tk + k] = v;
        }
    } else {
        // ---- m / u convert: 65536 float4, 1 per thread ----
        const int idx = (blk - 576) * 256 + tid;
        const int sec = idx >> 15;        // 0 = m, 1 = u
        const int j   = idx & 32767;
        const float4* src = sec ? (const float4*)(control + (size_t)BB * DIM)
                                : (const float4*)(memory  + (size_t)BB * DIM);
        float4 q = src[j];
        if (sec) {
            const float4 wa = ((const float4*)W_attn)[j & 127];
            q.x *= wa.x; q.y *= wa.y; q.z *= wa.z; q.w *= wa.w;
        }
        uint2 o;
        o.x = (unsigned)f2bf(q.x) | ((unsigned)f2bf(q.y) << 16);
        o.y = (unsigned)f2bf(q.z) | ((unsigned)f2bf(q.w) << 16);
        ((uint2*)mu)[(size_t)sec * 32768 + j] = o;
    }
}

// ---------------------------------------------------------------------------
// Kernel 1: prep via MFMA, k-split over blockIdx.z (2 halves) for occupancy:
// grid (16,16,2) = 512 blocks x 128 thr -> 2 blocks/CU, 4 waves/CU.
// Each block computes partial accM/acc1/acc2 over its k-half and atomicAdds
// into P[3][BB][DIM] (exactly 2 commutative f32 adds per addr -> bit-
// deterministic; P zeroed by memsetAsync each call). Bias + nonlinearity
// moved to read's prologue.
// Fragment maps (m89-verified): A lane l -> row=l&15, k=8*(l>>4)+j ;
// B lane l -> col=l&15, k same ; D lane l -> col=l&15, row=4*(l>>4)+reg.
// ---------------------------------------------------------------------------
__global__ __launch_bounds__(128) void prep_mfma(
    const ushort* __restrict__ Wt,    // [3][512][512] bf16
    const ushort* __restrict__ mu,    // [2][256][512] bf16
    float* __restrict__ P)            // [3][BB][DIM] partials (pre-zeroed)
{
    __shared__ __align__(16) ushort mus[2][16][264];   // k-half + 8 pad

    const int tid = threadIdx.x;     // 0..127
    const int wv  = tid >> 6;        // wave 0..1
    const int l   = tid & 63;        // lane
    const int b0  = blockIdx.x * 16;
    const int i0  = blockIdx.y * 32;
    const int k0  = blockIdx.z * 256;   // k-half base

    // stage m,u for 16 b rows, this k-half: 1024 uint4 by 128 threads
    #pragma unroll
    for (int p = 0; p < 8; ++p) {
        const int idx = p * 128 + tid;        // 0..1023
        const int a   = idx >> 9;             // 0..1 (m / u)
        const int rb  = (idx >> 5) & 15;      // b row
        const int kc  = (idx & 31) * 8;       // k offset (ushorts) in half
        *(uint4*)&mus[a][rb][kc] =
            *(const uint4*)&mu[((size_t)a * BB + b0 + rb) * DIM + k0 + kc];
    }
    __syncthreads();

    const int fr = l & 15;           // A row (b) / B col (i) / D col (i)
    const int fk = (l >> 4) * 8;     // k offset within 32-step

    f32x4 accM = {0.f, 0.f, 0.f, 0.f};
    f32x4 acc1 = {0.f, 0.f, 0.f, 0.f};
    f32x4 acc2 = {0.f, 0.f, 0.f, 0.f};

    const int ib = i0 + wv * 16 + fr;                    // this lane's i
    const ushort* wm = Wt + ((size_t)0 * DIM + ib) * DIM + k0;
    const ushort* c1 = Wt + ((size_t)1 * DIM + ib) * DIM + k0;
    const ushort* c2 = Wt + ((size_t)2 * DIM + ib) * DIM + k0;

    #pragma unroll 4
    for (int t = 0; t < 8; ++t) {
        const int k = t * 32 + fk;
        const bf16x8 am = *(const bf16x8*)&mus[0][fr][k];
        const bf16x8 au = *(const bf16x8*)&mus[1][fr][k];
        const bf16x8 bm = *(const bf16x8*)&wm[k];
        const bf16x8 b1 = *(const bf16x8*)&c1[k];
        const bf16x8 b2 = *(const bf16x8*)&c2[k];
        accM = __builtin_amdgcn_mfma_f32_16x16x32_bf16(am, bm, accM, 0, 0, 0);
        acc1 = __builtin_amdgcn_mfma_f32_16x16x32_bf16(au, b1, acc1, 0, 0, 0);
        acc2 = __builtin_amdgcn_mfma_f32_16x16x32_bf16(au, b2, acc2, 0, 0, 0);
    }

    const int rb0 = (l >> 4) * 4;
    #pragma unroll
    for (int r = 0; r < 4; ++r) {
        const size_t row = (size_t)(b0 + rb0 + r) * DIM + ib;
        atomicAdd(&P[row],                         accM[r]);
        atomicAdd(&P[(size_t)BB * DIM + row],      acc1[r]);
        atomicAdd(&P[(size_t)2 * BB * DIM + row],  acc2[r]);
    }
}

// ---------------------------------------------------------------------------
// Kernel 2: read — streaming loop byte-identical to r6; prologue now combines
// the 3 partial planes: w = (P0 + b_mem) * P1 + P2.
// ---------------------------------------------------------------------------
__global__ __launch_bounds__(1024) void read_kernel_p(
    const float* __restrict__ know,  // (BB, DIM, NN)
    const float* __restrict__ P,     // [3][BB][DIM]
    const float* __restrict__ b_mem, // (DIM)
    float* __restrict__ out)         // (BB, NN)
{
    __shared__ float  w_s[DIM];
    __shared__ float4 part_lg[16][50];
    __shared__ float4 part_ks[16][50];
    __shared__ float  tmp[256];
    __shared__ float  bc[2];

    const int tx  = threadIdx.x;       // 0..63 (lane)
    const int ty  = threadIdx.y;       // 0..15 (wave)
    const int tid = ty * 64 + tx;
    const int b   = blockIdx.x;

    if (tid < DIM) {
        const size_t row = (size_t)b * DIM + tid;
        w_s[tid] = (P[row] + b_mem[tid]) * P[(size_t)BB * DIM + row]
                 + P[(size_t)2 * BB * DIM + row];
    }
    __syncthreads();

    float4 lg = make_float4(0.f, 0.f, 0.f, 0.f);
    float4 ks = make_float4(0.f, 0.f, 0.f, 0.f);
    if (tx < 49) {
        const float4* kp = (const float4*)(know + (size_t)b * DIM * NN) + (size_t)(ty * 32) * 49 + tx;
        const float*  wp = w_s + ty * 32;
        #pragma unroll 8
        for (int dd = 0; dd < 32; ++dd) {
            const float4 kv = kp[(size_t)dd * 49];
            const float  wv = wp[dd];
            lg.x = fmaf(kv.x, wv, lg.x); lg.y = fmaf(kv.y, wv, lg.y);
            lg.z = fmaf(kv.z, wv, lg.z); lg.w = fmaf(kv.w, wv, lg.w);
            ks.x += kv.x; ks.y += kv.y; ks.z += kv.z; ks.w += kv.w;
        }
        part_lg[ty][tx] = lg;
        part_ks[ty][tx] = ks;
    }
    __syncthreads();

    float lgn = 0.f, ksn = 0.f;
    if (tid < NN) {
        const int ng = tid >> 2, j = tid & 3;
        #pragma unroll
        for (int t = 0; t < 16; ++t) {
            lgn += ((const float*)&part_lg[t][ng])[j];
            ksn += ((const float*)&part_ks[t][ng])[j];
        }
    }

    if (tid < 256) tmp[tid] = (tid < NN) ? lgn : -FLT_MAX;
    __syncthreads();
    if (tid < 64) {
        float m = fmaxf(fmaxf(tmp[tid], tmp[tid + 64]),
                        fmaxf(tmp[tid + 128], tmp[tid + 192]));
        #pragma unroll
        for (int o = 32; o; o >>= 1) m = fmaxf(m, __shfl_down(m, o));
        if (tid == 0) bc[0] = m;
    }
    __syncthreads();

    const float e = (tid < NN) ? __expf(lgn - bc[0]) : 0.f;
    if (tid < 256) tmp[tid] = e;
    __syncthreads();
    if (tid < 64) {
        float s = tmp[tid] + tmp[tid + 64] + tmp[tid + 128] + tmp[tid + 192];
        #pragma unroll
        for (int o = 32; o; o >>= 1) s += __shfl_down(s, o);
        if (tid == 0) bc[1] = s;
    }
    __syncthreads();

    if (tid < NN) out[(size_t)b * NN + tid] = e / bc[1] * ksn;
}

// ---------------------------------------------------------------------------
// Fallback path (r11 f32 prep + r6 read) — only if ws_size too small.
// ---------------------------------------------------------------------------
__global__ __launch_bounds__(512, 4) void prep_fallback(
    const float* __restrict__ memory, const float* __restrict__ control,
    const float* __restrict__ W_mem, const float* __restrict__ b_mem,
    const float* __restrict__ W_concat, const float* __restrict__ W_attn,
    float* __restrict__ w_out)
{
    __shared__ float4 MU4[4][DIM];
    __shared__ float  buf[12288];

    const int tid = threadIdx.x;
    const int il  = tid & 31;
    const int kg  = tid >> 5;
    const int b0  = blockIdx.x * 8;
    const int i0  = blockIdx.y * 32;

    const float* mem_in = memory  + (size_t)BB * DIM;
    const float* ctl_in = control + (size_t)BB * DIM;

    {
        const float wa = W_attn[tid];
        #pragma unroll
        for (int p = 0; p < 4; ++p) {
            MU4[p][tid] = make_float4(
                mem_in[(size_t)(b0 + 2 * p)     * DIM + tid],
                ctl_in[(size_t)(b0 + 2 * p)     * DIM + tid] * wa,
                mem_in[(size_t)(b0 + 2 * p + 1) * DIM + tid],
                ctl_in[(size_t)(b0 + 2 * p + 1) * DIM + tid] * wa);
        }
    }

    float am[8] = {}, a1[8] = {}, a2[8] = {};
    const int sr = tid >> 4;
    const int sc = tid & 15;
    float2* WT = (float2*)buf;

    float4 f1 = *(const float4*)&W_concat[(size_t)(i0 + sr) * DIM + sc * 4];
    float4 f2 = *(const float4*)&W_concat[(size_t)(DIM + i0 + sr) * DIM + sc * 4];
    float wmc[4], wmn[4];
    #pragma unroll
    for (int j = 0; j < 4; ++j)
        wmc[j] = W_mem[(size_t)(kg * 4 + j) * DIM + i0 + il];

    for (int kt = 0; kt < DIM; kt += 64) {
        __syncthreads();
        {
            const float* f1f = (const float*)&f1;
            const float* f2f = (const float*)&f2;
            #pragma unroll
            for (int j = 0; j < 4; ++j)
                WT[(sc * 4 + j) * 33 + sr] = make_float2(f1f[j], f2f[j]);
        }
        if (kt + 64 < DIM) {
            f1 = *(const float4*)&W_concat[(size_t)(i0 + sr) * DIM + kt + 64 + sc * 4];
            f2 = *(const float4*)&W_concat[(size_t)(DIM + i0 + sr) * DIM + kt + 64 + sc * 4];
        }
        __syncthreads();
        if (kt + 64 < DIM) {
            #pragma unroll
            for (int j = 0; j < 4; ++j)
                wmn[j] = W_mem[(size_t)(kt + 64 + kg * 4 + j) * DIM + i0 + il];
        }
        #pragma unroll
        for (int j = 0; j < 4; ++j) {
            const int kl = kg * 4 + j;
            const int k  = kt + kl;
            const float2 c = WT[kl * 33 + il];
            #pragma unroll
            for (int p = 0; p < 4; ++p) {
                const float4 muv = MU4[p][k];
                am[2*p]   = fmaf(muv.x, wmc[j], am[2*p]);
                a1[2*p]   = fmaf(muv.y, c.x,    a1[2*p]);
                a2[2*p]   = fmaf(muv.y, c.y,    a2[2*p]);
                am[2*p+1] = fmaf(muv.z, wmc[j], am[2*p+1]);
                a1[2*p+1] = fmaf(muv.w, c.x,    a1[2*p+1]);
                a2[2*p+1] = fmaf(muv.w, c.y,    a2[2*p+1]);
            }
        }
        #pragma unroll
        for (int j = 0; j < 4; ++j) wmc[j] = wmn[j];
    }

    __syncthreads();
    #pragma unroll
    for (int b = 0; b < 8; ++b) {
        const int row = (kg * 8 + b) * 32 + il;
        buf[row]        = am[b];
        buf[4096 + row] = a1[b];
        buf[8192 + row] = a2[b];
    }
    __syncthreads();
    if (tid < 256) {
        const int rb = tid >> 5, ri = tid & 31;
        float sm = 0.f, s1 = 0.f, s2 = 0.f;
        #pragma unroll
        for (int t = 0; t < 16; ++t) {
            const int row = (t * 8 + rb) * 32 + ri;
            sm += buf[row];
            s1 += buf[4096 + row];
            s2 += buf[8192 + row];
        }
        w_out[(size_t)(b0 + rb) * DIM + i0 + ri] =
            (sm + b_mem[i0 + ri]) * s1 + s2;
    }
}

__global__ __launch_bounds__(1024) void read_kernel_w(
    const float* __restrict__ know, const float* __restrict__ w,
    float* __restrict__ out)
{
    __shared__ float  w_s[DIM];
    __shared__ float4 part_lg[16][50];
    __shared__ float4 part_ks[16][50];
    __shared__ float  tmp[256];
    __shared__ float  bc[2];

    const int tx  = threadIdx.x;
    const int ty  = threadIdx.y;
    const int tid = ty * 64 + tx;
    const int b   = blockIdx.x;

    if (tid < DIM) w_s[tid] = w[(size_t)b * DIM + tid];
    __syncthreads();

    float4 lg = make_float4(0.f, 0.f, 0.f, 0.f);
    float4 ks = make_float4(0.f, 0.f, 0.f, 0.f);
    if (tx < 49) {
        const float4* kp = (const float4*)(know + (size_t)b * DIM * NN) + (size_t)(ty * 32) * 49 + tx;
        const float*  wp = w_s + ty * 32;
        #pragma unroll 8
        for (int dd = 0; dd < 32; ++dd) {
            const float4 kv = kp[(size_t)dd * 49];
            const float  wv = wp[dd];
            lg.x = fmaf(kv.x, wv, lg.x); lg.y = fmaf(kv.y, wv, lg.y);
            lg.z = fmaf(kv.z, wv, lg.z); lg.w = fmaf(kv.w, wv, lg.w);
            ks.x += kv.x; ks.y += kv.y; ks.z += kv.z; ks.w += kv.w;
        }
        part_lg[ty][tx] = lg;
        part_ks[ty][tx] = ks;
    }
    __syncthreads();

    float lgn = 0.f, ksn = 0.f;
    if (tid < NN) {
        const int ng = tid >> 2, j = tid & 3;
        #pragma unroll
        for (int t = 0; t < 16; ++t) {
            lgn += ((const float*)&part_lg[t][ng])[j];
            ksn += ((const float*)&part_ks[t][ng])[j];
        }
    }

    if (tid < 256) tmp[tid] = (tid < NN) ? lgn : -FLT_MAX;
    __syncthreads();
    if (tid < 64) {
        float m = fmaxf(fmaxf(tmp[tid], tmp[tid + 64]),
                        fmaxf(tmp[tid + 128], tmp[tid + 192]));
        #pragma unroll
        for (int o = 32; o; o >>= 1) m = fmaxf(m, __shfl_down(m, o));
        if (tid == 0) bc[0] = m;
    }
    __syncthreads();

    const float e = (tid < NN) ? __expf(lgn - bc[0]) : 0.f;
    if (tid < 256) tmp[tid] = e;
    __syncthreads();
    if (tid < 64) {
        float s = tmp[tid] + tmp[tid + 64] + tmp[tid + 128] + tmp[tid + 192];
        #pragma unroll
        for (int o = 32; o; o >>= 1) s += __shfl_down(s, o);
        if (tid == 0) bc[1] = s;
    }
    __syncthreads();

    if (tid < NN) out[(size_t)b * NN + tid] = e / bc[1] * ksn;
}

// ---------------------------------------------------------------------------
extern "C" void kernel_launch(void* const* d_in, const int* in_sizes, int n_in,
                              void* d_out, int out_size, void* d_ws, size_t ws_size,
                              hipStream_t stream) {
    const float* memory   = (const float*)d_in[0];
    const float* know     = (const float*)d_in[1];
    const float* control  = (const float*)d_in[2];
    const float* W_mem    = (const float*)d_in[3];
    const float* b_mem    = (const float*)d_in[4];
    const float* W_concat = (const float*)d_in[5];
    // d_in[6] = b_concat : uniform over n -> softmax-invariant, unused
    const float* W_attn   = (const float*)d_in[7];
    // d_in[8] = b_attn   : same, unused
    float* outp = (float*)d_out;

    const size_t P_BYTES  = (size_t)3 * BB * DIM * sizeof(float);    // 1.5 MB
    const size_t WT_BYTES = (size_t)3 * DIM * DIM * sizeof(ushort);  // 1.5 MB
    const size_t MU_BYTES = (size_t)2 * BB * DIM * sizeof(ushort);   // 512 KB

    if (ws_size >= P_BYTES + WT_BYTES + MU_BYTES) {
        float*  Pp = (float*)d_ws;
        ushort* Wt = (ushort*)((char*)d_ws + P_BYTES);
        ushort* mu = (ushort*)((char*)d_ws + P_BYTES + WT_BYTES);
        hipMemsetAsync(Pp, 0, P_BYTES, stream);
        convert_kernel<<<dim3(832), dim3(256), 0, stream>>>(
            memory, control, W_mem, W_concat, W_attn, Wt, mu);
        prep_mfma<<<dim3(BB / 16, DIM / 32, 2), dim3(128), 0, stream>>>(
            Wt, mu, Pp);
        read_kernel_p<<<dim3(BB), dim3(64, 16), 0, stream>>>(
            know, Pp, b_mem, outp);
    } else {
        float* w_ws = (float*)d_ws;
        prep_fallback<<<dim3(BB / 8, DIM / 32), dim3(512), 0, stream>>>(
            memory, control, W_mem, b_mem, W_concat, W_attn, w_ws);
        read_kernel_w<<<dim3(BB), dim3(64, 16), 0, stream>>>(know, w_ws, outp);
    }
}

// Round 15
// 32.873 us; speedup vs baseline: 1.1247x; 1.1247x over previous
//
#include <hip/hip_runtime.h>
#include <cfloat>

// Problem dims (fixed by reference)
#define BB   256   // batch
#define DIM  512
#define NN   196

typedef __attribute__((ext_vector_type(8))) short bf16x8;   // 8 bf16 (4 VGPRs)
typedef __attribute__((ext_vector_type(4))) float f32x4;    // MFMA acc

__device__ __forceinline__ ushort f2bf(float x) {          // RNE f32->bf16
    unsigned u = __float_as_uint(x);
    return (ushort)((u + 0x7FFFu + ((u >> 16) & 1u)) >> 16);
}

// ---------------------------------------------------------------------------
// Kernel 0: convert — build bf16 operands in d_ws.  832 blocks
// (512 Wc + 64 WmT + 256 mu) ~ 3.3 blocks/CU, 13 waves/CU (r14's re-grid,
// now measured in isolation vs r13's 256-block 1-block/CU version).
//   Wt[0][i][k] = bf16(W_mem[k][i])  (transposed)
//   Wt[1][i][k] = bf16(W_concat[i][k]) ; Wt[2][i][k] = bf16(W_concat[DIM+i][k])
//   mu[0][b][k] = bf16(memory[-1][b][k]) ; mu[1][b][k] = bf16(ctl[-1][b][k]*W_attn[k])
// ---------------------------------------------------------------------------
__global__ __launch_bounds__(256) void convert_kernel(
    const float* __restrict__ memory, const float* __restrict__ control,
    const float* __restrict__ W_mem, const float* __restrict__ W_concat,
    const float* __restrict__ W_attn,
    ushort* __restrict__ Wt,      // [3][512][512] bf16
    ushort* __restrict__ mu)      // [2][256][512] bf16
{
    const int tid = threadIdx.x;
    const int blk = blockIdx.x;

    if (blk < 512) {
        // ---- W_concat straight convert: 131072 float4, 1 per thread ----
        const int idx = blk * 256 + tid;
        const float4 q = ((const float4*)W_concat)[idx];
        uint2 o;
        o.x = (unsigned)f2bf(q.x) | ((unsigned)f2bf(q.y) << 16);
        o.y = (unsigned)f2bf(q.z) | ((unsigned)f2bf(q.w) << 16);
        ((uint2*)(Wt + (size_t)DIM * DIM))[idx] = o;
    } else if (blk < 576) {
        // ---- W_mem transpose-convert, 64x64 tile via LDS ----
        __shared__ float T[64][65];
        const int t  = blk - 512;
        const int tk = (t >> 3) * 64, ti = (t & 7) * 64;
        const int r  = tid >> 2;            // k-local row
        const int cb = (tid & 3) * 16;      // i-local col base
        #pragma unroll
        for (int j = 0; j < 16; j += 4) {
            const float4 q = *(const float4*)&W_mem[(size_t)(tk + r) * DIM + ti + cb + j];
            T[r][cb + j + 0] = q.x; T[r][cb + j + 1] = q.y;
            T[r][cb + j + 2] = q.z; T[r][cb + j + 3] = q.w;
        }
        __syncthreads();
        const int ii = tid & 63;            // i-local
        const int kq = tid >> 6;            // 0..3
        #pragma unroll
        for (int kk = 0; kk < 16; kk += 2) {
            const int k = kq * 16 + kk;
            const unsigned v = (unsigned)f2bf(T[k][ii]) | ((unsigned)f2bf(T[k + 1][ii]) << 16);
            *(unsigned*)&Wt[(size_t)(ti + ii) * DIM + tk + k] = v;
        }
    } else {
        // ---- m / u convert: 65536 float4, 1 per thread ----
        const int idx = (blk - 576) * 256 + tid;
        const int sec = idx >> 15;        // 0 = m, 1 = u
        const int j   = idx & 32767;
        const float4* src = sec ? (const float4*)(control + (size_t)BB * DIM)
                                : (const float4*)(memory  + (size_t)BB * DIM);
        float4 q = src[j];
        if (sec) {
            const float4 wa = ((const float4*)W_attn)[j & 127];
            q.x *= wa.x; q.y *= wa.y; q.z *= wa.z; q.w *= wa.w;
        }
        uint2 o;
        o.x = (unsigned)f2bf(q.x) | ((unsigned)f2bf(q.y) << 16);
        o.y = (unsigned)f2bf(q.z) | ((unsigned)f2bf(q.w) << 16);
        ((uint2*)mu)[(size_t)sec * 32768 + j] = o;
    }
}

// ---------------------------------------------------------------------------
// Kernel 1: prep via MFMA (r13-proven, single-k, direct w write).
// Three GEMMs D[b,i] = A[b,k]·B[k,i], A in {m,u}, B = Wt rows. 16x16x32 bf16,
// 16 k-steps, 3 MFMA/step. grid (16,16) x 128 thr (wave = one 16i sub-tile).
// Fragment maps (m89-verified): A lane l -> row=l&15, k=8*(l>>4)+j ;
// B lane l -> col=l&15, k same ; D lane l -> col=l&15, row=4*(l>>4)+reg.
// ---------------------------------------------------------------------------
__global__ __launch_bounds__(128) void prep_mfma(
    const ushort* __restrict__ Wt,    // [3][512][512] bf16
    const ushort* __restrict__ mu,    // [2][256][512] bf16
    const float* __restrict__ b_mem,  // (DIM)
    float* __restrict__ w_out)        // (BB, DIM)
{
    __shared__ __align__(16) ushort mus[2][16][520];   // +8 pad: row stride 1040B

    const int tid = threadIdx.x;     // 0..127
    const int wv  = tid >> 6;        // wave 0..1
    const int l   = tid & 63;        // lane
    const int b0  = blockIdx.x * 16;
    const int i0  = blockIdx.y * 32;

    // stage m,u for 16 b rows: 2048 uint4 by 128 threads
    #pragma unroll
    for (int p = 0; p < 16; ++p) {
        const int idx = p * 128 + tid;        // 0..2047
        const int a   = idx >> 10;            // 0..1 (m / u)
        const int rb  = (idx >> 6) & 15;      // b row
        const int kc  = (idx & 63) * 8;       // k offset (ushorts)
        *(uint4*)&mus[a][rb][kc] =
            *(const uint4*)&mu[((size_t)a * BB + b0 + rb) * DIM + kc];
    }
    __syncthreads();

    const int fr = l & 15;           // A row (b) / B col (i) / D col (i)
    const int fk = (l >> 4) * 8;     // k offset within 32-step

    f32x4 accM = {0.f, 0.f, 0.f, 0.f};
    f32x4 acc1 = {0.f, 0.f, 0.f, 0.f};
    f32x4 acc2 = {0.f, 0.f, 0.f, 0.f};

    const int ib = i0 + wv * 16 + fr;                    // this lane's i
    const ushort* wm = Wt + ((size_t)0 * DIM + ib) * DIM;
    const ushort* c1 = Wt + ((size_t)1 * DIM + ib) * DIM;
    const ushort* c2 = Wt + ((size_t)2 * DIM + ib) * DIM;

    #pragma unroll 4
    for (int t = 0; t < 16; ++t) {
        const int k = t * 32 + fk;
        const bf16x8 am = *(const bf16x8*)&mus[0][fr][k];
        const bf16x8 au = *(const bf16x8*)&mus[1][fr][k];
        const bf16x8 bm = *(const bf16x8*)&wm[k];
        const bf16x8 b1 = *(const bf16x8*)&c1[k];
        const bf16x8 b2 = *(const bf16x8*)&c2[k];
        accM = __builtin_amdgcn_mfma_f32_16x16x32_bf16(am, bm, accM, 0, 0, 0);
        acc1 = __builtin_amdgcn_mfma_f32_16x16x32_bf16(au, b1, acc1, 0, 0, 0);
        acc2 = __builtin_amdgcn_mfma_f32_16x16x32_bf16(au, b2, acc2, 0, 0, 0);
    }

    const float bmv = b_mem[ib];
    const int rb0 = (l >> 4) * 4;
    #pragma unroll
    for (int r = 0; r < 4; ++r) {
        w_out[(size_t)(b0 + rb0 + r) * DIM + ib] =
            (accM[r] + bmv) * acc1[r] + acc2[r];
    }
}

// ---------------------------------------------------------------------------
// Kernel 1-fallback (r11-proven f32 prep) — only if ws_size too small.
// ---------------------------------------------------------------------------
__global__ __launch_bounds__(512, 4) void prep_fallback(
    const float* __restrict__ memory, const float* __restrict__ control,
    const float* __restrict__ W_mem, const float* __restrict__ b_mem,
    const float* __restrict__ W_concat, const float* __restrict__ W_attn,
    float* __restrict__ w_out)
{
    __shared__ float4 MU4[4][DIM];
    __shared__ float  buf[12288];

    const int tid = threadIdx.x;
    const int il  = tid & 31;
    const int kg  = tid >> 5;
    const int b0  = blockIdx.x * 8;
    const int i0  = blockIdx.y * 32;

    const float* mem_in = memory  + (size_t)BB * DIM;
    const float* ctl_in = control + (size_t)BB * DIM;

    {
        const float wa = W_attn[tid];
        #pragma unroll
        for (int p = 0; p < 4; ++p) {
            MU4[p][tid] = make_float4(
                mem_in[(size_t)(b0 + 2 * p)     * DIM + tid],
                ctl_in[(size_t)(b0 + 2 * p)     * DIM + tid] * wa,
                mem_in[(size_t)(b0 + 2 * p + 1) * DIM + tid],
                ctl_in[(size_t)(b0 + 2 * p + 1) * DIM + tid] * wa);
        }
    }

    float am[8] = {}, a1[8] = {}, a2[8] = {};
    const int sr = tid >> 4;
    const int sc = tid & 15;
    float2* WT = (float2*)buf;

    float4 f1 = *(const float4*)&W_concat[(size_t)(i0 + sr) * DIM + sc * 4];
    float4 f2 = *(const float4*)&W_concat[(size_t)(DIM + i0 + sr) * DIM + sc * 4];
    float wmc[4], wmn[4];
    #pragma unroll
    for (int j = 0; j < 4; ++j)
        wmc[j] = W_mem[(size_t)(kg * 4 + j) * DIM + i0 + il];

    for (int kt = 0; kt < DIM; kt += 64) {
        __syncthreads();
        {
            const float* f1f = (const float*)&f1;
            const float* f2f = (const float*)&f2;
            #pragma unroll
            for (int j = 0; j < 4; ++j)
                WT[(sc * 4 + j) * 33 + sr] = make_float2(f1f[j], f2f[j]);
        }
        if (kt + 64 < DIM) {
            f1 = *(const float4*)&W_concat[(size_t)(i0 + sr) * DIM + kt + 64 + sc * 4];
            f2 = *(const float4*)&W_concat[(size_t)(DIM + i0 + sr) * DIM + kt + 64 + sc * 4];
        }
        __syncthreads();
        if (kt + 64 < DIM) {
            #pragma unroll
            for (int j = 0; j < 4; ++j)
                wmn[j] = W_mem[(size_t)(kt + 64 + kg * 4 + j) * DIM + i0 + il];
        }
        #pragma unroll
        for (int j = 0; j < 4; ++j) {
            const int kl = kg * 4 + j;
            const int k  = kt + kl;
            const float2 c = WT[kl * 33 + il];
            #pragma unroll
            for (int p = 0; p < 4; ++p) {
                const float4 muv = MU4[p][k];
                am[2*p]   = fmaf(muv.x, wmc[j], am[2*p]);
                a1[2*p]   = fmaf(muv.y, c.x,    a1[2*p]);
                a2[2*p]   = fmaf(muv.y, c.y,    a2[2*p]);
                am[2*p+1] = fmaf(muv.z, wmc[j], am[2*p+1]);
                a1[2*p+1] = fmaf(muv.w, c.x,    a1[2*p+1]);
                a2[2*p+1] = fmaf(muv.w, c.y,    a2[2*p+1]);
            }
        }
        #pragma unroll
        for (int j = 0; j < 4; ++j) wmc[j] = wmn[j];
    }

    __syncthreads();
    #pragma unroll
    for (int b = 0; b < 8; ++b) {
        const int row = (kg * 8 + b) * 32 + il;
        buf[row]        = am[b];
        buf[4096 + row] = a1[b];
        buf[8192 + row] = a2[b];
    }
    __syncthreads();
    if (tid < 256) {
        const int rb = tid >> 5, ri = tid & 31;
        float sm = 0.f, s1 = 0.f, s2 = 0.f;
        #pragma unroll
        for (int t = 0; t < 16; ++t) {
            const int row = (t * 8 + rb) * 32 + ri;
            sm += buf[row];
            s1 += buf[4096 + row];
            s2 += buf[8192 + row];
        }
        w_out[(size_t)(b0 + rb) * DIM + i0 + ri] =
            (sm + b_mem[i0 + ri]) * s1 + s2;
    }
}

// ---------------------------------------------------------------------------
// Kernel 2: per-b streaming pass over know (float4, 16 waves/block).
// (byte-identical to round 6 — best proven read)
// ---------------------------------------------------------------------------
__global__ __launch_bounds__(1024) void read_kernel(
    const float* __restrict__ know,  // (BB, DIM, NN)
    const float* __restrict__ w,     // (BB, DIM)
    float* __restrict__ out)         // (BB, NN)
{
    __shared__ float  w_s[DIM];
    __shared__ float4 part_lg[16][50];
    __shared__ float4 part_ks[16][50];
    __shared__ float  tmp[256];
    __shared__ float  bc[2];

    const int tx  = threadIdx.x;       // 0..63 (lane)
    const int ty  = threadIdx.y;       // 0..15 (wave)
    const int tid = ty * 64 + tx;
    const int b   = blockIdx.x;

    if (tid < DIM) w_s[tid] = w[(size_t)b * DIM + tid];
    __syncthreads();

    float4 lg = make_float4(0.f, 0.f, 0.f, 0.f);
    float4 ks = make_float4(0.f, 0.f, 0.f, 0.f);
    if (tx < 49) {
        const float4* kp = (const float4*)(know + (size_t)b * DIM * NN) + (size_t)(ty * 32) * 49 + tx;
        const float*  wp = w_s + ty * 32;
        #pragma unroll 8
        for (int dd = 0; dd < 32; ++dd) {
            const float4 kv = kp[(size_t)dd * 49];
            const float  wv = wp[dd];
            lg.x = fmaf(kv.x, wv, lg.x); lg.y = fmaf(kv.y, wv, lg.y);
            lg.z = fmaf(kv.z, wv, lg.z); lg.w = fmaf(kv.w, wv, lg.w);
            ks.x += kv.x; ks.y += kv.y; ks.z += kv.z; ks.w += kv.w;
        }
        part_lg[ty][tx] = lg;
        part_ks[ty][tx] = ks;
    }
    __syncthreads();

    float lgn = 0.f, ksn = 0.f;
    if (tid < NN) {
        const int ng = tid >> 2, j = tid & 3;
        #pragma unroll
        for (int t = 0; t < 16; ++t) {
            lgn += ((const float*)&part_lg[t][ng])[j];
            ksn += ((const float*)&part_ks[t][ng])[j];
        }
    }

    if (tid < 256) tmp[tid] = (tid < NN) ? lgn : -FLT_MAX;
    __syncthreads();
    if (tid < 64) {
        float m = fmaxf(fmaxf(tmp[tid], tmp[tid + 64]),
                        fmaxf(tmp[tid + 128], tmp[tid + 192]));
        #pragma unroll
        for (int o = 32; o; o >>= 1) m = fmaxf(m, __shfl_down(m, o));
        if (tid == 0) bc[0] = m;
    }
    __syncthreads();

    const float e = (tid < NN) ? __expf(lgn - bc[0]) : 0.f;
    if (tid < 256) tmp[tid] = e;
    __syncthreads();
    if (tid < 64) {
        float s = tmp[tid] + tmp[tid + 64] + tmp[tid + 128] + tmp[tid + 192];
        #pragma unroll
        for (int o = 32; o; o >>= 1) s += __shfl_down(s, o);
        if (tid == 0) bc[1] = s;
    }
    __syncthreads();

    if (tid < NN) out[(size_t)b * NN + tid] = e / bc[1] * ksn;
}

// ---------------------------------------------------------------------------
extern "C" void kernel_launch(void* const* d_in, const int* in_sizes, int n_in,
                              void* d_out, int out_size, void* d_ws, size_t ws_size,
                              hipStream_t stream) {
    const float* memory   = (const float*)d_in[0];
    const float* know     = (const float*)d_in[1];
    const float* control  = (const float*)d_in[2];
    const float* W_mem    = (const float*)d_in[3];
    const float* b_mem    = (const float*)d_in[4];
    const float* W_concat = (const float*)d_in[5];
    // d_in[6] = b_concat : uniform over n -> softmax-invariant, unused
    const float* W_attn   = (const float*)d_in[7];
    // d_in[8] = b_attn   : same, unused
    float* outp = (float*)d_out;

    const size_t W_BYTES  = (size_t)BB * DIM * sizeof(float);        // 512 KB
    const size_t WT_BYTES = (size_t)3 * DIM * DIM * sizeof(ushort);  // 1.5 MB
    const size_t MU_BYTES = (size_t)2 * BB * DIM * sizeof(ushort);   // 512 KB

    float* w_ws = (float*)d_ws;

    if (ws_size >= W_BYTES + WT_BYTES + MU_BYTES) {
        ushort* Wt = (ushort*)((char*)d_ws + W_BYTES);
        ushort* mu = (ushort*)((char*)d_ws + W_BYTES + WT_BYTES);
        convert_kernel<<<dim3(832), dim3(256), 0, stream>>>(
            memory, control, W_mem, W_concat, W_attn, Wt, mu);
        prep_mfma<<<dim3(BB / 16, DIM / 32), dim3(128), 0, stream>>>(
            Wt, mu, b_mem, w_ws);
    } else {
        prep_fallback<<<dim3(BB / 8, DIM / 32), dim3(512), 0, stream>>>(
            memory, control, W_mem, b_mem, W_concat, W_attn, w_ws);
    }
    read_kernel<<<dim3(BB), dim3(64, 16), 0, stream>>>(know, w_ws, outp);
}